// Round 9
// baseline (434.617 us; speedup 1.0000x reference)
//
#include <hip/hip_runtime.h>
#include <math.h>

// Problem constants
#define Bc 8
#define Hc 32
#define Fc 8
#define Xc 128
#define Tc 256

typedef __bf16 bf16x8 __attribute__((ext_vector_type(8)));
typedef float f32x4 __attribute__((ext_vector_type(4)));

__device__ __forceinline__ int bitrev7(int x) { return (int)(__brev((unsigned)x) >> 25); }

// pack two floats as bf16 (RNE): a in low 16, b in high 16
__device__ __forceinline__ unsigned pack_bf16(float a, float b) {
    unsigned ua = __float_as_uint(a);
    unsigned ub = __float_as_uint(b);
    ua = (ua + 0x7FFFu + ((ua >> 16) & 1u)) >> 16;
    ub = (ub + 0x7FFFu + ((ub >> 16) & 1u)) & 0xFFFF0000u;
    return (ua & 0xFFFFu) | ub;
}
// float value of bf16(a) (RNE)
__device__ __forceinline__ float bf16_val(float a) {
    unsigned ua = __float_as_uint(a);
    ua = (ua + 0x7FFFu + ((ua >> 16) & 1u)) & 0xFFFF0000u;
    return __uint_as_float(ua);
}

// One radix-2 DIT butterfly, arithmetic identical to the original stage loop.
__device__ __forceinline__ void bfly(float2& a, float2& b, float2 twv, float sign) {
    float cs = twv.x, sn = sign * twv.y;
    float2 bw = make_float2(cs * b.x - sn * b.y, cs * b.y + sn * b.x);
    float2 na = make_float2(a.x + bw.x, a.y + bw.y);
    b = make_float2(a.x - bw.x, a.y - bw.y);
    a = na;
}

// ---- FFT LDS layout: element e of row r lives at r*RS + e + (e>>3) ----
// 1 pad slot per 8 elements; RS=144 so ALL 16 pad slots (9k+8, k=0..15,
// max 143) are in-row. (R8 bug: RS=143 made slot 143 alias the next row's
// element 0 -> twiddles with (t&15)==15 clobbered/were clobbered -> NaN.)
// Twiddles are stashed IN the pad slots: tw[t] at row t>>4, slot 9*(t&15)+8.
// Bounds: AIX(127)=142<144, TWA max=143<144, phase-3 max AIX(31)+108=142. OK.
#define RS 144
__device__ __forceinline__ int AIX(int e) { return e + (e >> 3); }
__device__ __forceinline__ int TWA(int t) { return (t >> 4) * RS + (t & 15) * 9 + 8; }

__device__ __forceinline__ void fft_tw_init(float2* c, int tid) {
    if (tid >= 1 && tid < 128) {
        int h = 1 << (31 - __builtin_clz((unsigned)tid));
        int pos = tid - h;
        float sn, cs;
        __sincosf(3.14159265358979f * (float)pos / (float)h, &sn, &cs);
        c[TWA(tid)] = make_float2(cs, sn);
    }
}

// Phases 1 (half=1,2,4) and 2 (half=8,16). Caller must sync before (stage +
// tw visible) and after (before phase 3). Same butterflies / twiddles / order
// as the radix-2 reference loop -> bit-identical.
template <int NTHR>
__device__ __forceinline__ void fft_ph12(float2* c, float sign, int tid) {
    float2 t1 = c[TWA(1)], t2 = c[TWA(2)], t3 = c[TWA(3)];
    float2 t4 = c[TWA(4)], t5 = c[TWA(5)], t6 = c[TWA(6)], t7 = c[TWA(7)];
    for (int grp = tid; grp < 32 * 16; grp += NTHR) {
        float2* p = c + (grp >> 4) * RS + (grp & 15) * 9;
        float2 v[8];
#pragma unroll
        for (int e = 0; e < 8; ++e) v[e] = p[e];
        bfly(v[0], v[1], t1, sign); bfly(v[2], v[3], t1, sign);
        bfly(v[4], v[5], t1, sign); bfly(v[6], v[7], t1, sign);
        bfly(v[0], v[2], t2, sign); bfly(v[1], v[3], t3, sign);
        bfly(v[4], v[6], t2, sign); bfly(v[5], v[7], t3, sign);
        bfly(v[0], v[4], t4, sign); bfly(v[1], v[5], t5, sign);
        bfly(v[2], v[6], t6, sign); bfly(v[3], v[7], t7, sign);
#pragma unroll
        for (int e = 0; e < 8; ++e) p[e] = v[e];
    }
    __syncthreads();
    for (int grp = tid; grp < 32 * 32; grp += NTHR) {
        int row = grp >> 5, sub = grp & 31;
        int m = sub & 7, k = sub >> 3;
        float2* p = c + row * RS + 36 * k + m;  // a(32k+m)=36k+m; +8 -> +9 etc.
        float2 v0 = p[0], v1 = p[9], v2 = p[18], v3 = p[27];
        float2 ta = c[TWA(8 + m)], tb = c[TWA(16 + m)], tc_ = c[TWA(24 + m)];
        bfly(v0, v1, ta, sign);
        bfly(v2, v3, ta, sign);
        bfly(v0, v2, tb, sign);
        bfly(v1, v3, tc_, sign);
        p[0] = v0; p[9] = v1; p[18] = v2; p[27] = v3;
    }
    // caller syncs, then runs phase 3 (half=32,64) fused with its store
}

// K-1: transpose xi (b,f): [X][T] -> [T][X] so k_spec's xi read is coalesced.
__global__ void k_xit(const float* __restrict__ xi, float* __restrict__ xiT) {
    __shared__ float tile[32][33];
    int bid = blockIdx.x;  // (b*Fc+f)*8 + tt
    int bf = bid >> 3, tt = bid & 7;
    int t0 = tt * 32;
    int tid = threadIdx.x;
    for (int xt = 0; xt < 4; ++xt) {
        int x0 = xt * 32;
        __syncthreads();
        for (int idx = tid; idx < 1024; idx += 256) {
            int xr = idx >> 5, tc = idx & 31;
            tile[xr][tc] = xi[((size_t)bf * Xc + x0 + xr) * Tc + t0 + tc];
        }
        __syncthreads();
        for (int idx = tid; idx < 1024; idx += 256) {
            int tr = idx >> 5, xc = idx & 31;
            xiT[((size_t)bf * Tc + t0 + tr) * Xc + x0 + xc] = tile[xc][tr];
        }
    }
}

// K0: Fz/Gz precompute + FFT(z0); phase 3 fused with the Z0ft store
// (lanes vary h -> coalesced 32-lane float2 runs).
__global__ void k_pre(const float* __restrict__ z0, const float* __restrict__ A,
                      const float* __restrict__ Gw, float* __restrict__ Fz,
                      float* __restrict__ Gz, float2* __restrict__ Z0ft) {
    __shared__ float z0l[Hc * Xc];
    __shared__ float2 cbuf[Hc * RS];
    int b = blockIdx.x;
    int tid = threadIdx.x;
    for (int idx = tid; idx < Hc * Xc; idx += 256) z0l[idx] = z0[b * Hc * Xc + idx];
    fft_tw_init(cbuf, tid);
    __syncthreads();
    for (int idx = tid; idx < Hc * Xc; idx += 256) {
        int i = idx >> 7, x = idx & 127;
        float s = 0.f;
        for (int h = 0; h < Hc; ++h) s += A[i * Hc + h] * z0l[h * 128 + x];
        Fz[b * Hc * Xc + idx] = s;
    }
    for (int idx = tid; idx < Hc * Fc * Xc; idx += 256) {
        int i = idx >> 10, f = (idx >> 7) & 7, x = idx & 127;
        float s = 0.f;
        for (int h = 0; h < Hc; ++h) s += Gw[(i * Fc + f) * Hc + h] * z0l[h * 128 + x];
        Gz[b * Hc * Fc * Xc + idx] = s;
    }
    for (int idx = tid; idx < Hc * Xc; idx += 256) {
        int h = idx >> 7, x = idx & 127;
        cbuf[h * RS + AIX(bitrev7(x))] = make_float2(z0l[h * 128 + x], 0.f);
    }
    __syncthreads();
    fft_ph12<256>(cbuf, -1.f, tid);
    __syncthreads();
    for (int grp = tid; grp < 1024; grp += 256) {
        int h = grp & 31, m2 = grp >> 5;
        float2* p = cbuf + h * RS + AIX(m2);
        float2 v0 = p[0], v1 = p[36], v2 = p[72], v3 = p[108];
        float2 ta = cbuf[TWA(32 + m2)], tb = cbuf[TWA(64 + m2)], tc_ = cbuf[TWA(96 + m2)];
        bfly(v0, v1, ta, -1.f);
        bfly(v2, v3, ta, -1.f);
        bfly(v0, v2, tb, -1.f);
        bfly(v1, v3, tc_, -1.f);
        // element e -> xs = e^64 (fftshift)
        Z0ft[(b * Xc + m2 + 64) * Hc + h] = v0;
        Z0ft[(b * Xc + m2 + 96) * Hc + h] = v1;
        Z0ft[(b * Xc + m2) * Hc + h] = v2;
        Z0ft[(b * Xc + m2 + 32) * Hc + h] = v3;
    }
}

// K1: per (b,t): Hu = Fz + sum_f Gz*xi; Hft[b][xs][t][i] = fftshift(fft_x(Hu))
// Phase 3 fused with the Hft store (lanes vary i -> coalesced).
// LDS = 4096 + 32*144*8 = 40,960 B -> exactly 4 blocks/CU.
__global__ void k_spec(const float* __restrict__ xiT, const float* __restrict__ Fz,
                       const float* __restrict__ Gz, float2* __restrict__ Hft) {
    __shared__ float xil[Fc * Xc];
    __shared__ float2 cbuf[Hc * RS];
    int bid = blockIdx.x;
    int b = bid >> 8, t = bid & 255;
    int tid = threadIdx.x;
    for (int idx = tid; idx < Fc * Xc / 4; idx += 512) {
        int f = idx >> 5, xq = (idx & 31) * 4;
        *(float4*)(xil + f * 128 + xq) =
            *(const float4*)(xiT + ((size_t)(b * Fc + f) * Tc + t) * Xc + xq);
    }
    fft_tw_init(cbuf, tid);
    __syncthreads();
    for (int idx = tid; idx < Hc * Xc / 4; idx += 512) {
        int i = idx >> 5, xq = (idx & 31) * 4;
        float4 hu = *(const float4*)(Fz + b * Hc * Xc + i * 128 + xq);
        const float* gzp = Gz + (b * Hc + i) * (Fc * Xc) + xq;
#pragma unroll
        for (int f = 0; f < Fc; ++f) {
            float4 gz = *(const float4*)(gzp + f * 128);
            float4 xv = *(const float4*)(&xil[f * 128 + xq]);
            hu.x += gz.x * xv.x; hu.y += gz.y * xv.y;
            hu.z += gz.z * xv.z; hu.w += gz.w * xv.w;
        }
        cbuf[i * RS + AIX(bitrev7(xq + 0))] = make_float2(hu.x, 0.f);
        cbuf[i * RS + AIX(bitrev7(xq + 1))] = make_float2(hu.y, 0.f);
        cbuf[i * RS + AIX(bitrev7(xq + 2))] = make_float2(hu.z, 0.f);
        cbuf[i * RS + AIX(bitrev7(xq + 3))] = make_float2(hu.w, 0.f);
    }
    __syncthreads();
    fft_ph12<512>(cbuf, -1.f, tid);
    __syncthreads();
    for (int grp = tid; grp < 1024; grp += 512) {
        int i = grp & 31, m2 = grp >> 5;
        float2* p = cbuf + i * RS + AIX(m2);
        float2 v0 = p[0], v1 = p[36], v2 = p[72], v3 = p[108];
        float2 ta = cbuf[TWA(32 + m2)], tb = cbuf[TWA(64 + m2)], tc_ = cbuf[TWA(96 + m2)];
        bfly(v0, v1, ta, -1.f);
        bfly(v2, v3, ta, -1.f);
        bfly(v0, v2, tb, -1.f);
        bfly(v1, v3, tc_, -1.f);
        // element e -> xs = e^64 (fftshift)
        Hft[((long)(b * Xc + m2 + 64) * Tc + t) * Hc + i] = v0;
        Hft[((long)(b * Xc + m2 + 96) * Tc + t) * Hc + i] = v1;
        Hft[((long)(b * Xc + m2) * Tc + t) * Hc + i] = v2;
        Hft[((long)(b * Xc + m2 + 32) * Tc + t) * Hc + i] = v3;
    }
}

// ---- k_scan LDS layout (bytes) ----
// Mlf : 0      .. 131584  (2 bufs x 16 planes x 1028 dwords)
// Bd  : 131584 .. 140800  (2 bufs x 1152 dwords: Bhi 16x36 + Blo 16x36)
// zlf : 140800 .. 141824  (4 chains x 32 float2)
// zst : 141824 .. 150016  (4 chains x 8 t-slots x 32 float2)
#define ML_DW 16448
#define B_DW  1152
#define SCAN_LDS 150016

__device__ __forceinline__ void build_B(unsigned* Bb, int w, int tt, int c,
                                        float2 hp, float2 hn, float sc) {
    float dre = (hn.x - hp.x) * sc;
    float dim = (hn.y - hp.y) * sc;
    float hre = bf16_val(dre), hmim = bf16_val(-dim), him = bf16_val(dim);
    int n0 = w * 4 + tt * 2;
    Bb[n0 * 36 + c] = pack_bf16(hre, hmim);               // re-out col hi
    Bb[(n0 + 1) * 36 + c] = pack_bf16(him, hre);          // im-out col hi
    Bb[576 + n0 * 36 + c] = pack_bf16(dre - hre, (-dim) - hmim);
    Bb[576 + (n0 + 1) * 36 + c] = pack_bf16(dim - him, dre - hre);
}

// K3: frozen at R7 state (structural plateau: LDS pipe ~70% occupied by
// intrinsic M movement; bf16-M and scan-composition are numerically dead).
__global__ __launch_bounds__(768, 3) void k_scan(const float* __restrict__ Wr,
                                                 const float* __restrict__ Wi,
                                                 const float2* __restrict__ Hft,
                                                 const float2* __restrict__ Z0ft,
                                                 float2* __restrict__ Zall) {
    extern __shared__ unsigned char smem[];
    float* Mlf = (float*)smem;
    unsigned* Aw = (unsigned*)smem;               // staging alias [1024 rows][32]
    unsigned* Bd = (unsigned*)(smem + 131584);
    float* zlf = (float*)(smem + 140800);
    float2* zstc = (float2*)(smem + 141824);

    int tid = threadIdx.x;
    int x = blockIdx.x >> 1, g = blockIdx.x & 1;
    int lane = tid & 63, wid = tid >> 6;
    int isProd = (wid < 8);
    int p = wid;                                  // producer row-band index 0..7
    int w = isProd ? (wid & 3) : (wid - 8);       // chain index (consumer)
    int b = g * 4 + w;

    // ---- stage W as packed bf16 complex, swizzled for A-frag reads (all 12 waves) ----
    const float* wrp = Wr + (size_t)x * 32768;
    const float* wip = Wi + (size_t)x * 32768;
    for (int idx = tid; idx < 32768; idx += 768) {
        int j = idx & 31, cc = (idx >> 5) & 31, ii = idx >> 10;
        int r = ii * 32 + j;  // GEMM row = i*32 + j
        int pd = r * 32 + (((cc >> 2) ^ (r & 7)) << 2) + (cc & 3);
        Aw[pd] = pack_bf16(wrp[(ii * 32 + cc) * 32 + j], wip[(ii * 32 + cc) * 32 + j]);
    }
    __syncthreads();

    size_t bx = (size_t)(b * Xc + x);
    const float2* Hrow = Hft + bx * (Tc * Hc);  // [t][c]
    float2* Zrow = Zall + bx * (Hc * Tc);       // [i][t]
    int jq = lane >> 5, il = lane & 31;         // scan roles; also (tt, c) for B/H

    uint4 af[8][2];
    float2 Hp2 = make_float2(0.f, 0.f), Hn2 = make_float2(0.f, 0.f);
    float2 zr = make_float2(0.f, 0.f);

    if (isProd) {
        // ---- persistent A-fragments: producer p owns rows p*128..p*128+127 ----
        int n16 = lane & 15, q = lane >> 4;
        int rbase = p * 128 + n16;
#pragma unroll
        for (int mt = 0; mt < 8; ++mt) {
            int r = rbase + mt * 16;
#pragma unroll
            for (int kf = 0; kf < 2; ++kf) {
                int cg = (kf * 4 + q) ^ (r & 7);
                af[mt][kf] = *(const uint4*)(Aw + r * 32 + cg * 4);
            }
        }
    } else {
        // consumer: priority boost (serial-latency-critical wave), z init,
        // B(0) + H(chunk 1) prefetch
        __builtin_amdgcn_s_setprio(1);
        zr = Z0ft[bx * Hc + il];
        if (jq == 0) {
            ((float2*)(zlf + w * 64))[il] = zr;
            zstc[w * 256 + il] = zr;  // t=0 slot
        }
        float2 ha = Hrow[jq * 32 + il];
        float2 hb = Hrow[(1 + jq) * 32 + il];
        build_B(Bd, w, jq, il, ha, hb, 1.f);
        Hp2 = Hrow[(2 + jq) * 32 + il];
        Hn2 = Hrow[(3 + jq) * 32 + il];
    }
    __syncthreads();  // publishes af-reads-of-Aw done, B(0), zl/zst init

#pragma unroll 1
    for (int k = 0; k <= 128; ++k) {
        if (isProd) {
            if (k < 128) {
                int bk = k & 1;
                // ---- cooperative MFMA: M(chunk k) for all 4 chains ----
                int n = lane & 15, q = lane >> 4;
                const unsigned* Bb = Bd + bk * B_DW;
                bf16x8 bh0 = __builtin_bit_cast(bf16x8, *(const uint4*)(Bb + n * 36 + q * 4));
                bf16x8 bh1 = __builtin_bit_cast(bf16x8, *(const uint4*)(Bb + n * 36 + 16 + q * 4));
                bf16x8 bl0 = __builtin_bit_cast(bf16x8, *(const uint4*)(Bb + 576 + n * 36 + q * 4));
                bf16x8 bl1 = __builtin_bit_cast(bf16x8, *(const uint4*)(Bb + 576 + n * 36 + 16 + q * 4));
                float* Mb = Mlf + bk * ML_DW;
#pragma unroll
                for (int mt = 0; mt < 8; ++mt) {
                    f32x4 acc = {0.f, 0.f, 0.f, 0.f};
                    acc = __builtin_amdgcn_mfma_f32_16x16x32_bf16(
                        __builtin_bit_cast(bf16x8, af[mt][0]), bh0, acc, 0, 0, 0);
                    acc = __builtin_amdgcn_mfma_f32_16x16x32_bf16(
                        __builtin_bit_cast(bf16x8, af[mt][1]), bh1, acc, 0, 0, 0);
                    acc = __builtin_amdgcn_mfma_f32_16x16x32_bf16(
                        __builtin_bit_cast(bf16x8, af[mt][0]), bl0, acc, 0, 0, 0);
                    acc = __builtin_amdgcn_mfma_f32_16x16x32_bf16(
                        __builtin_bit_cast(bf16x8, af[mt][1]), bl1, acc, 0, 0, 0);
                    int i = p * 4 + (mt >> 1);
                    int jgp = ((((mt & 1) * 4) + q) ^ (i & 7)) ^ ((i >> 3) & 3);
                    *(f32x4*)(Mb + n * 1028 + i * 32 + jgp * 4) = acc;
                }
            }
        } else {
            // ---- consumer: prefetch H(chunk k+2), retire M(k-1), build B(k+1) ----
            float2 HpN = Hp2, HnN = Hn2;
            if (k + 2 <= 127) {
                int kc2 = k + 2;
                HpN = Hrow[(2 * kc2 + jq) * 32 + il];
                int t2 = 2 * kc2 + 1 + jq;
                if (t2 > 255) t2 = 255;
                HnN = Hrow[t2 * 32 + il];
            }
            if (k > 0) {
                int kc = k - 1;
                int bk = kc & 1;
#pragma unroll
                for (int s = 0; s < 2; ++s) {
                    int t = 2 * kc + 1 + s;
                    if (t > 255) break;
                    const float* base = Mlf + bk * ML_DW + (w * 4 + s * 2) * 1028 + il * 32;
                    float4 mr[4], mi[4];
#pragma unroll
                    for (int gg = 0; gg < 4; ++gg) {
                        int jg = (((jq * 4 + gg) ^ (il & 7) ^ ((il >> 3) & 3)) << 2);
                        mr[gg] = *(const float4*)(base + jg);
                        mi[gg] = *(const float4*)(base + 1028 + jg);
                    }
                    const float4* zf4 = (const float4*)(zlf + w * 64);
                    float yR = 0.f, yI = 0.f;
#pragma unroll
                    for (int gg = 0; gg < 4; ++gg) {
                        float4 za = zf4[jq * 8 + gg * 2];
                        float4 zb = zf4[jq * 8 + gg * 2 + 1];
                        yR += mr[gg].x * za.x - mi[gg].x * za.y + mr[gg].y * za.z - mi[gg].y * za.w
                            + mr[gg].z * zb.x - mi[gg].z * zb.y + mr[gg].w * zb.z - mi[gg].w * zb.w;
                        yI += mr[gg].x * za.y + mi[gg].x * za.x + mr[gg].y * za.w + mi[gg].y * za.z
                            + mr[gg].z * zb.y + mi[gg].z * zb.x + mr[gg].w * zb.w + mi[gg].w * zb.z;
                    }
                    yR += __shfl_xor(yR, 32);
                    yI += __shfl_xor(yI, 32);
                    zr.x += yR;
                    zr.y += yI;
                    if (jq == 0) {
                        ((float2*)(zlf + w * 64))[il] = zr;
                        zstc[w * 256 + (t & 7) * 32 + il] = zr;
                    }
                    if ((t & 7) == 7) {  // flush 8 t-slots, coalesced
                        int t0 = t - 7;
                        int i2 = lane >> 1, tb = (lane & 1) * 4;
                        float2 v0 = zstc[w * 256 + (tb + 0) * 32 + i2];
                        float2 v1 = zstc[w * 256 + (tb + 1) * 32 + i2];
                        float2 v2 = zstc[w * 256 + (tb + 2) * 32 + i2];
                        float2 v3 = zstc[w * 256 + (tb + 3) * 32 + i2];
                        *(float4*)(Zrow + i2 * Tc + t0 + tb) = make_float4(v0.x, v0.y, v1.x, v1.y);
                        *(float4*)(Zrow + i2 * Tc + t0 + tb + 2) = make_float4(v2.x, v2.y, v3.x, v3.y);
                    }
                }
            }
            // build B(k+1) into buf (k+1)&1 from regs fetched at k-1
            if (k < 127) {
                float sc = (2 * (k + 1) + 1 + jq <= 255) ? 1.f : 0.f;
                build_B(Bd + ((k + 1) & 1) * B_DW, w, jq, il, Hp2, Hn2, sc);
                Hp2 = HpN;
                Hn2 = HnN;
            }
        }
        __syncthreads();  // hand off M(k) / B(k+1); consumers done with M(k-1)
    }
}

// K4: per (b,i,tchunk): ifftshift + ifft_x + real -> out[b][i][x][t]
// Phase 3 fused with the out store (lanes vary tc -> coalesced).
__global__ void k_post(const float2* __restrict__ Zall, float* __restrict__ out) {
    __shared__ float2 cbuf[32 * RS];
    int bid = blockIdx.x;
    int b = bid >> 8, i = (bid >> 3) & 31, tq = bid & 7;
    int t0 = tq * 32;
    int tid = threadIdx.x;
    for (int idx = tid; idx < 128 * 16; idx += 512) {
        int k = idx >> 4, tc2 = (idx & 15) * 2;
        int xg = (k + 64) & 127;
        float4 v = *(const float4*)(Zall + ((long)(b * Xc + xg) * Hc + i) * Tc + t0 + tc2);
        int ka = AIX(bitrev7(k));
        cbuf[tc2 * RS + ka] = make_float2(v.x, v.y);
        cbuf[(tc2 + 1) * RS + ka] = make_float2(v.z, v.w);
    }
    fft_tw_init(cbuf, tid);   // pads only; never aliases element slots (RS=144)
    __syncthreads();
    fft_ph12<512>(cbuf, +1.f, tid);
    __syncthreads();
    const float inv = 1.0f / 128.0f;
    for (int grp = tid; grp < 1024; grp += 512) {
        int tc = grp & 31, m2 = grp >> 5;
        float2* p = cbuf + tc * RS + AIX(m2);
        float2 v0 = p[0], v1 = p[36], v2 = p[72], v3 = p[108];
        float2 ta = cbuf[TWA(32 + m2)], tb = cbuf[TWA(64 + m2)], tc_ = cbuf[TWA(96 + m2)];
        bfly(v0, v1, ta, +1.f);
        bfly(v2, v3, ta, +1.f);
        bfly(v0, v2, tb, +1.f);
        bfly(v1, v3, tc_, +1.f);
        // input was pre-ifftshifted -> element e stores at xs = e
        long ob = ((long)(b * Hc + i) * Xc) * Tc + t0 + tc;
        out[ob + (long)(m2) * Tc] = v0.x * inv;
        out[ob + (long)(m2 + 32) * Tc] = v1.x * inv;
        out[ob + (long)(m2 + 64) * Tc] = v2.x * inv;
        out[ob + (long)(m2 + 96) * Tc] = v3.x * inv;
    }
}

extern "C" void kernel_launch(void* const* d_in, const int* in_sizes, int n_in,
                              void* d_out, int out_size, void* d_ws, size_t ws_size,
                              hipStream_t stream) {
    const float* z0 = (const float*)d_in[0];
    const float* xi = (const float*)d_in[1];
    const float* A = (const float*)d_in[2];
    const float* Gw = (const float*)d_in[3];
    const float* Wr = (const float*)d_in[4];
    const float* Wi = (const float*)d_in[5];
    float* out = (float*)d_out;
    char* ws = (char*)d_ws;

    float2* Hft = (float2*)(ws);                      // 67,108,864 B
    float2* Zall = (float2*)(ws + 67108864);          // 67,108,864 B
    float2* Z0ft = (float2*)(ws + 134217728);         // 262,144 B
    float* Fz = (float*)(ws + 134479872);             // 131,072 B
    float* Gz = (float*)(ws + 134610944);             // 1,048,576 B
    // xiT (8 MB) aliases the START of the Zall region: consumed by k_spec,
    // then fully overwritten by k_scan before k_post reads Zall.
    float* xiT = (float*)(ws + 67108864);

    (void)hipFuncSetAttribute((const void*)k_scan,
                              hipFuncAttributeMaxDynamicSharedMemorySize, SCAN_LDS);

    k_xit<<<Bc * Fc * 8, 256, 0, stream>>>(xi, xiT);
    k_pre<<<Bc, 256, 0, stream>>>(z0, A, Gw, Fz, Gz, Z0ft);
    k_spec<<<Bc * Tc, 512, 0, stream>>>(xiT, Fz, Gz, Hft);
    k_scan<<<Xc * 2, 768, SCAN_LDS, stream>>>(Wr, Wi, Hft, Z0ft, Zall);
    k_post<<<Bc * Hc * 8, 512, 0, stream>>>(Zall, out);
}

// Round 10
// 411.852 us; speedup vs baseline: 1.0553x; 1.0553x over previous
//
#include <hip/hip_runtime.h>
#include <math.h>

// Problem constants
#define Bc 8
#define Hc 32
#define Fc 8
#define Xc 128
#define Tc 256

typedef __bf16 bf16x8 __attribute__((ext_vector_type(8)));
typedef float f32x4 __attribute__((ext_vector_type(4)));

__device__ __forceinline__ int bitrev7(int x) { return (int)(__brev((unsigned)x) >> 25); }

// pack two floats as bf16 (RNE): a in low 16, b in high 16
__device__ __forceinline__ unsigned pack_bf16(float a, float b) {
    unsigned ua = __float_as_uint(a);
    unsigned ub = __float_as_uint(b);
    ua = (ua + 0x7FFFu + ((ua >> 16) & 1u)) >> 16;
    ub = (ub + 0x7FFFu + ((ub >> 16) & 1u)) & 0xFFFF0000u;
    return (ua & 0xFFFFu) | ub;
}
// float value of bf16(a) (RNE)
__device__ __forceinline__ float bf16_val(float a) {
    unsigned ua = __float_as_uint(a);
    ua = (ua + 0x7FFFu + ((ua >> 16) & 1u)) & 0xFFFF0000u;
    return __uint_as_float(ua);
}

// One radix-2 DIT butterfly, arithmetic identical to the original stage loop.
__device__ __forceinline__ void bfly(float2& a, float2& b, float2 twv, float sign) {
    float cs = twv.x, sn = sign * twv.y;
    float2 bw = make_float2(cs * b.x - sn * b.y, cs * b.y + sn * b.x);
    float2 na = make_float2(a.x + bw.x, a.y + bw.y);
    b = make_float2(a.x - bw.x, a.y - bw.y);
    a = na;
}

// In-place radix-2 DIT FFT over 32 rows x 128 complex (input bit-reversed).
// Row stride 129 float2 (odd) -> row-to-row bank rotation: kills the
// stride-1KB column conflicts in the callers' epilogue loops. Same
// butterflies / twiddles / order as the radix-2 loop -> bit-identical.
#define FRS 129
template <int NTHR>
__device__ __forceinline__ void fft32x128(float2* buf, float sign) {
    __shared__ float2 tw[128];
    int tid = threadIdx.x;
    if (tid >= 1 && tid < 128) {
        int h = 1 << (31 - __builtin_clz((unsigned)tid));
        int pos = tid - h;
        float sn, cs;
        __sincosf(3.14159265358979f * (float)pos / (float)h, &sn, &cs);
        tw[tid] = make_float2(cs, sn);
    }
    __syncthreads();
    // Phase 1: stages half=1,2,4 on 8 consecutive elements per group.
    for (int grp = tid; grp < 32 * 16; grp += NTHR) {
        float2* p = buf + (grp >> 4) * FRS + (grp & 15) * 8;
        float2 v[8];
#pragma unroll
        for (int e = 0; e < 8; ++e) v[e] = p[e];
        bfly(v[0], v[1], tw[1], sign); bfly(v[2], v[3], tw[1], sign);
        bfly(v[4], v[5], tw[1], sign); bfly(v[6], v[7], tw[1], sign);
        bfly(v[0], v[2], tw[2], sign); bfly(v[1], v[3], tw[3], sign);
        bfly(v[4], v[6], tw[2], sign); bfly(v[5], v[7], tw[3], sign);
        bfly(v[0], v[4], tw[4], sign); bfly(v[1], v[5], tw[5], sign);
        bfly(v[2], v[6], tw[6], sign); bfly(v[3], v[7], tw[7], sign);
#pragma unroll
        for (int e = 0; e < 8; ++e) p[e] = v[e];
    }
    __syncthreads();
    // Phase 2: stages half=8,16.
    for (int grp = tid; grp < 32 * 32; grp += NTHR) {
        int row = grp >> 5, sub = grp & 31;
        int m = sub & 7, k = sub >> 3;
        float2* p = buf + row * FRS + k * 32 + m;
        float2 v0 = p[0], v1 = p[8], v2 = p[16], v3 = p[24];
        bfly(v0, v1, tw[8 + m], sign);
        bfly(v2, v3, tw[8 + m], sign);
        bfly(v0, v2, tw[16 + m], sign);
        bfly(v1, v3, tw[16 + m + 8], sign);
        p[0] = v0; p[8] = v1; p[16] = v2; p[24] = v3;
    }
    __syncthreads();
    // Phase 3: stages half=32,64.
    for (int grp = tid; grp < 32 * 32; grp += NTHR) {
        int row = grp >> 5, m2 = grp & 31;
        float2* p = buf + row * FRS + m2;
        float2 v0 = p[0], v1 = p[32], v2 = p[64], v3 = p[96];
        bfly(v0, v1, tw[32 + m2], sign);
        bfly(v2, v3, tw[32 + m2], sign);
        bfly(v0, v2, tw[64 + m2], sign);
        bfly(v1, v3, tw[64 + m2 + 32], sign);
        p[0] = v0; p[32] = v1; p[64] = v2; p[96] = v3;
    }
    __syncthreads();
}

// K-1: transpose xi (b,f): [X][T] -> [T][X] so k_spec's xi read is coalesced.
__global__ void k_xit(const float* __restrict__ xi, float* __restrict__ xiT) {
    __shared__ float tile[32][33];
    int bid = blockIdx.x;  // (b*Fc+f)*8 + tt
    int bf = bid >> 3, tt = bid & 7;
    int t0 = tt * 32;
    int tid = threadIdx.x;
    for (int xt = 0; xt < 4; ++xt) {
        int x0 = xt * 32;
        __syncthreads();
        for (int idx = tid; idx < 1024; idx += 256) {
            int xr = idx >> 5, tc = idx & 31;
            tile[xr][tc] = xi[((size_t)bf * Xc + x0 + xr) * Tc + t0 + tc];
        }
        __syncthreads();
        for (int idx = tid; idx < 1024; idx += 256) {
            int tr = idx >> 5, xc = idx & 31;
            xiT[((size_t)bf * Tc + t0 + tr) * Xc + x0 + xc] = tile[xc][tr];
        }
    }
}

// K0: Fz/Gz precompute + FFT(z0)
__global__ void k_pre(const float* __restrict__ z0, const float* __restrict__ A,
                      const float* __restrict__ Gw, float* __restrict__ Fz,
                      float* __restrict__ Gz, float2* __restrict__ Z0ft) {
    __shared__ float z0l[Hc * Xc];
    __shared__ float2 cbuf[Hc * FRS];
    int b = blockIdx.x;
    int tid = threadIdx.x;
    for (int idx = tid; idx < Hc * Xc; idx += 256) z0l[idx] = z0[b * Hc * Xc + idx];
    __syncthreads();
    for (int idx = tid; idx < Hc * Xc; idx += 256) {
        int i = idx >> 7, x = idx & 127;
        float s = 0.f;
        for (int h = 0; h < Hc; ++h) s += A[i * Hc + h] * z0l[h * 128 + x];
        Fz[b * Hc * Xc + idx] = s;
    }
    for (int idx = tid; idx < Hc * Fc * Xc; idx += 256) {
        int i = idx >> 10, f = (idx >> 7) & 7, x = idx & 127;
        float s = 0.f;
        for (int h = 0; h < Hc; ++h) s += Gw[(i * Fc + f) * Hc + h] * z0l[h * 128 + x];
        Gz[b * Hc * Fc * Xc + idx] = s;
    }
    for (int idx = tid; idx < Hc * Xc; idx += 256) {
        int h = idx >> 7, x = idx & 127;
        cbuf[h * FRS + bitrev7(x)] = make_float2(z0l[h * 128 + x], 0.f);
    }
    fft32x128<256>(cbuf, -1.f);
    for (int idx = tid; idx < Xc * Hc; idx += 256) {
        int xs = idx >> 5, h = idx & 31;
        Z0ft[(b * Xc + xs) * Hc + h] = cbuf[h * FRS + ((xs + 64) & 127)];
    }
}

// K1: per (b,t): Hu = Fz + sum_f Gz*xi; Hft[b][xs][t][i] = fftshift(fft_x(Hu))
// float4 global loads; cbuf stride FRS for conflict-free epilogue.
__global__ void k_spec(const float* __restrict__ xiT, const float* __restrict__ Fz,
                       const float* __restrict__ Gz, float2* __restrict__ Hft) {
    __shared__ float xil[Fc * Xc];
    __shared__ float2 cbuf[Hc * FRS];
    int bid = blockIdx.x;
    int b = bid >> 8, t = bid & 255;
    int tid = threadIdx.x;
    for (int idx = tid; idx < Fc * Xc / 4; idx += 512) {
        int f = idx >> 5, xq = (idx & 31) * 4;
        *(float4*)(xil + f * 128 + xq) =
            *(const float4*)(xiT + ((size_t)(b * Fc + f) * Tc + t) * Xc + xq);
    }
    __syncthreads();
    for (int idx = tid; idx < Hc * Xc / 4; idx += 512) {
        int i = idx >> 5, xq = (idx & 31) * 4;
        float4 hu = *(const float4*)(Fz + b * Hc * Xc + i * 128 + xq);
        const float* gzp = Gz + (b * Hc + i) * (Fc * Xc) + xq;
#pragma unroll
        for (int f = 0; f < Fc; ++f) {
            float4 gz = *(const float4*)(gzp + f * 128);
            float4 xv = *(const float4*)(&xil[f * 128 + xq]);
            hu.x += gz.x * xv.x; hu.y += gz.y * xv.y;
            hu.z += gz.z * xv.z; hu.w += gz.w * xv.w;
        }
        cbuf[i * FRS + bitrev7(xq + 0)] = make_float2(hu.x, 0.f);
        cbuf[i * FRS + bitrev7(xq + 1)] = make_float2(hu.y, 0.f);
        cbuf[i * FRS + bitrev7(xq + 2)] = make_float2(hu.z, 0.f);
        cbuf[i * FRS + bitrev7(xq + 3)] = make_float2(hu.w, 0.f);
    }
    fft32x128<512>(cbuf, -1.f);
    for (int idx = tid; idx < Xc * Hc; idx += 512) {
        int xs = idx >> 5, i = idx & 31;
        Hft[((long)(b * Xc + xs) * Tc + t) * Hc + i] = cbuf[i * FRS + ((xs + 64) & 127)];
    }
}

// ---- k_scan LDS layout (bytes) ----
// Mlf : 0      .. 131584  (2 bufs x 16 planes x 1028 dwords)
// Bd  : 131584 .. 140800  (2 bufs x 1152 dwords: Bhi 16x36 + Blo 16x36)
// zlf : 140800 .. 141824  (4 chains x 32 float2)
// zst : 141824 .. 150016  (4 chains x 8 t-slots x 32 float2)
#define ML_DW 16448
#define B_DW  1152
#define SCAN_LDS 150016

__device__ __forceinline__ void build_B(unsigned* Bb, int w, int tt, int c,
                                        float2 hp, float2 hn, float sc) {
    float dre = (hn.x - hp.x) * sc;
    float dim = (hn.y - hp.y) * sc;
    float hre = bf16_val(dre), hmim = bf16_val(-dim), him = bf16_val(dim);
    int n0 = w * 4 + tt * 2;
    Bb[n0 * 36 + c] = pack_bf16(hre, hmim);               // re-out col hi
    Bb[(n0 + 1) * 36 + c] = pack_bf16(him, hre);          // im-out col hi
    Bb[576 + n0 * 36 + c] = pack_bf16(dre - hre, (-dim) - hmim);
    Bb[576 + (n0 + 1) * 36 + c] = pack_bf16(dim - him, dre - hre);
}

// K3: 256 blocks (2 per x), 12 waves/block (768 thr), 1 block/CU.
// 8 producer waves (2/SIMD): MFMA M-build + M-store. 4 consumer waves
// (1/SIMD, setprio 1): serial scan + B-build + H-prefetch per chain.
// M slot swizzle ^((i>>3)&3): consumer's M-read bank quad depends on all 5
// row bits (conflicts 1.39e7 -> 5.5e6 measured). Structural plateau beyond
// this: LDS pipe ~70% occupied by intrinsic M movement; bf16-M and
// scan-composition are numerically dead (R5 lesson: summation order inside
// the 256-step recurrence is part of the interface).
__global__ __launch_bounds__(768, 3) void k_scan(const float* __restrict__ Wr,
                                                 const float* __restrict__ Wi,
                                                 const float2* __restrict__ Hft,
                                                 const float2* __restrict__ Z0ft,
                                                 float2* __restrict__ Zall) {
    extern __shared__ unsigned char smem[];
    float* Mlf = (float*)smem;
    unsigned* Aw = (unsigned*)smem;               // staging alias [1024 rows][32]
    unsigned* Bd = (unsigned*)(smem + 131584);
    float* zlf = (float*)(smem + 140800);
    float2* zstc = (float2*)(smem + 141824);

    int tid = threadIdx.x;
    int x = blockIdx.x >> 1, g = blockIdx.x & 1;
    int lane = tid & 63, wid = tid >> 6;
    int isProd = (wid < 8);
    int p = wid;                                  // producer row-band index 0..7
    int w = isProd ? (wid & 3) : (wid - 8);       // chain index (consumer)
    int b = g * 4 + w;

    // ---- stage W as packed bf16 complex, swizzled for A-frag reads (all 12 waves) ----
    const float* wrp = Wr + (size_t)x * 32768;
    const float* wip = Wi + (size_t)x * 32768;
    for (int idx = tid; idx < 32768; idx += 768) {
        int j = idx & 31, cc = (idx >> 5) & 31, ii = idx >> 10;
        int r = ii * 32 + j;  // GEMM row = i*32 + j
        int pd = r * 32 + (((cc >> 2) ^ (r & 7)) << 2) + (cc & 3);
        Aw[pd] = pack_bf16(wrp[(ii * 32 + cc) * 32 + j], wip[(ii * 32 + cc) * 32 + j]);
    }
    __syncthreads();

    size_t bx = (size_t)(b * Xc + x);
    const float2* Hrow = Hft + bx * (Tc * Hc);  // [t][c]
    float2* Zrow = Zall + bx * (Hc * Tc);       // [i][t]
    int jq = lane >> 5, il = lane & 31;         // scan roles; also (tt, c) for B/H

    uint4 af[8][2];
    float2 Hp2 = make_float2(0.f, 0.f), Hn2 = make_float2(0.f, 0.f);
    float2 zr = make_float2(0.f, 0.f);

    if (isProd) {
        // ---- persistent A-fragments: producer p owns rows p*128..p*128+127 ----
        int n16 = lane & 15, q = lane >> 4;
        int rbase = p * 128 + n16;
#pragma unroll
        for (int mt = 0; mt < 8; ++mt) {
            int r = rbase + mt * 16;
#pragma unroll
            for (int kf = 0; kf < 2; ++kf) {
                int cg = (kf * 4 + q) ^ (r & 7);
                af[mt][kf] = *(const uint4*)(Aw + r * 32 + cg * 4);
            }
        }
    } else {
        // consumer: priority boost (serial-latency-critical wave), z init,
        // B(0) + H(chunk 1) prefetch
        __builtin_amdgcn_s_setprio(1);
        zr = Z0ft[bx * Hc + il];
        if (jq == 0) {
            ((float2*)(zlf + w * 64))[il] = zr;
            zstc[w * 256 + il] = zr;  // t=0 slot
        }
        float2 ha = Hrow[jq * 32 + il];
        float2 hb = Hrow[(1 + jq) * 32 + il];
        build_B(Bd, w, jq, il, ha, hb, 1.f);
        Hp2 = Hrow[(2 + jq) * 32 + il];
        Hn2 = Hrow[(3 + jq) * 32 + il];
    }
    __syncthreads();  // publishes af-reads-of-Aw done, B(0), zl/zst init

#pragma unroll 1
    for (int k = 0; k <= 128; ++k) {
        if (isProd) {
            if (k < 128) {
                int bk = k & 1;
                // ---- cooperative MFMA: M(chunk k) for all 4 chains ----
                int n = lane & 15, q = lane >> 4;
                const unsigned* Bb = Bd + bk * B_DW;
                bf16x8 bh0 = __builtin_bit_cast(bf16x8, *(const uint4*)(Bb + n * 36 + q * 4));
                bf16x8 bh1 = __builtin_bit_cast(bf16x8, *(const uint4*)(Bb + n * 36 + 16 + q * 4));
                bf16x8 bl0 = __builtin_bit_cast(bf16x8, *(const uint4*)(Bb + 576 + n * 36 + q * 4));
                bf16x8 bl1 = __builtin_bit_cast(bf16x8, *(const uint4*)(Bb + 576 + n * 36 + 16 + q * 4));
                float* Mb = Mlf + bk * ML_DW;
#pragma unroll
                for (int mt = 0; mt < 8; ++mt) {
                    f32x4 acc = {0.f, 0.f, 0.f, 0.f};
                    acc = __builtin_amdgcn_mfma_f32_16x16x32_bf16(
                        __builtin_bit_cast(bf16x8, af[mt][0]), bh0, acc, 0, 0, 0);
                    acc = __builtin_amdgcn_mfma_f32_16x16x32_bf16(
                        __builtin_bit_cast(bf16x8, af[mt][1]), bh1, acc, 0, 0, 0);
                    acc = __builtin_amdgcn_mfma_f32_16x16x32_bf16(
                        __builtin_bit_cast(bf16x8, af[mt][0]), bl0, acc, 0, 0, 0);
                    acc = __builtin_amdgcn_mfma_f32_16x16x32_bf16(
                        __builtin_bit_cast(bf16x8, af[mt][1]), bl1, acc, 0, 0, 0);
                    int i = p * 4 + (mt >> 1);
                    int jgp = ((((mt & 1) * 4) + q) ^ (i & 7)) ^ ((i >> 3) & 3);
                    *(f32x4*)(Mb + n * 1028 + i * 32 + jgp * 4) = acc;
                }
            }
        } else {
            // ---- consumer: prefetch H(chunk k+2), retire M(k-1), build B(k+1) ----
            float2 HpN = Hp2, HnN = Hn2;
            if (k + 2 <= 127) {
                int kc2 = k + 2;
                HpN = Hrow[(2 * kc2 + jq) * 32 + il];
                int t2 = 2 * kc2 + 1 + jq;
                if (t2 > 255) t2 = 255;
                HnN = Hrow[t2 * 32 + il];
            }
            if (k > 0) {
                int kc = k - 1;
                int bk = kc & 1;
#pragma unroll
                for (int s = 0; s < 2; ++s) {
                    int t = 2 * kc + 1 + s;
                    if (t > 255) break;
                    const float* base = Mlf + bk * ML_DW + (w * 4 + s * 2) * 1028 + il * 32;
                    float4 mr[4], mi[4];
#pragma unroll
                    for (int gg = 0; gg < 4; ++gg) {
                        int jg = (((jq * 4 + gg) ^ (il & 7) ^ ((il >> 3) & 3)) << 2);
                        mr[gg] = *(const float4*)(base + jg);
                        mi[gg] = *(const float4*)(base + 1028 + jg);
                    }
                    const float4* zf4 = (const float4*)(zlf + w * 64);
                    float yR = 0.f, yI = 0.f;
#pragma unroll
                    for (int gg = 0; gg < 4; ++gg) {
                        float4 za = zf4[jq * 8 + gg * 2];
                        float4 zb = zf4[jq * 8 + gg * 2 + 1];
                        yR += mr[gg].x * za.x - mi[gg].x * za.y + mr[gg].y * za.z - mi[gg].y * za.w
                            + mr[gg].z * zb.x - mi[gg].z * zb.y + mr[gg].w * zb.z - mi[gg].w * zb.w;
                        yI += mr[gg].x * za.y + mi[gg].x * za.x + mr[gg].y * za.w + mi[gg].y * za.z
                            + mr[gg].z * zb.y + mi[gg].z * zb.x + mr[gg].w * zb.w + mi[gg].w * zb.z;
                    }
                    yR += __shfl_xor(yR, 32);
                    yI += __shfl_xor(yI, 32);
                    zr.x += yR;
                    zr.y += yI;
                    if (jq == 0) {
                        ((float2*)(zlf + w * 64))[il] = zr;
                        zstc[w * 256 + (t & 7) * 32 + il] = zr;
                    }
                    if ((t & 7) == 7) {  // flush 8 t-slots, coalesced
                        int t0 = t - 7;
                        int i2 = lane >> 1, tb = (lane & 1) * 4;
                        float2 v0 = zstc[w * 256 + (tb + 0) * 32 + i2];
                        float2 v1 = zstc[w * 256 + (tb + 1) * 32 + i2];
                        float2 v2 = zstc[w * 256 + (tb + 2) * 32 + i2];
                        float2 v3 = zstc[w * 256 + (tb + 3) * 32 + i2];
                        *(float4*)(Zrow + i2 * Tc + t0 + tb) = make_float4(v0.x, v0.y, v1.x, v1.y);
                        *(float4*)(Zrow + i2 * Tc + t0 + tb + 2) = make_float4(v2.x, v2.y, v3.x, v3.y);
                    }
                }
            }
            // build B(k+1) into buf (k+1)&1 from regs fetched at k-1
            if (k < 127) {
                float sc = (2 * (k + 1) + 1 + jq <= 255) ? 1.f : 0.f;
                build_B(Bd + ((k + 1) & 1) * B_DW, w, jq, il, Hp2, Hn2, sc);
                Hp2 = HpN;
                Hn2 = HnN;
            }
        }
        __syncthreads();  // hand off M(k) / B(k+1); consumers done with M(k-1)
    }
}

// K4: per (b,i,tchunk): ifftshift + ifft_x + real -> out[b][i][x][t]
// float4 Zall loads (2 t each); cbuf stride FRS for conflict-free epilogue.
__global__ void k_post(const float2* __restrict__ Zall, float* __restrict__ out) {
    __shared__ float2 cbuf[32 * FRS];
    int bid = blockIdx.x;
    int b = bid >> 8, i = (bid >> 3) & 31, tq = bid & 7;
    int t0 = tq * 32;
    int tid = threadIdx.x;
    for (int idx = tid; idx < 128 * 16; idx += 512) {
        int k = idx >> 4, tc2 = (idx & 15) * 2;
        int xg = (k + 64) & 127;
        float4 v = *(const float4*)(Zall + ((long)(b * Xc + xg) * Hc + i) * Tc + t0 + tc2);
        int kb = bitrev7(k);
        cbuf[tc2 * FRS + kb] = make_float2(v.x, v.y);
        cbuf[(tc2 + 1) * FRS + kb] = make_float2(v.z, v.w);
    }
    fft32x128<512>(cbuf, +1.f);
    const float inv = 1.0f / 128.0f;
    for (int idx = tid; idx < 128 * 32; idx += 512) {
        int xs = idx >> 5, tc = idx & 31;
        out[((long)(b * Hc + i) * Xc + xs) * Tc + t0 + tc] = cbuf[tc * FRS + xs].x * inv;
    }
}

extern "C" void kernel_launch(void* const* d_in, const int* in_sizes, int n_in,
                              void* d_out, int out_size, void* d_ws, size_t ws_size,
                              hipStream_t stream) {
    const float* z0 = (const float*)d_in[0];
    const float* xi = (const float*)d_in[1];
    const float* A = (const float*)d_in[2];
    const float* Gw = (const float*)d_in[3];
    const float* Wr = (const float*)d_in[4];
    const float* Wi = (const float*)d_in[5];
    float* out = (float*)d_out;
    char* ws = (char*)d_ws;

    float2* Hft = (float2*)(ws);                      // 67,108,864 B
    float2* Zall = (float2*)(ws + 67108864);          // 67,108,864 B
    float2* Z0ft = (float2*)(ws + 134217728);         // 262,144 B
    float* Fz = (float*)(ws + 134479872);             // 131,072 B
    float* Gz = (float*)(ws + 134610944);             // 1,048,576 B
    // xiT (8 MB) aliases the START of the Zall region: consumed by k_spec,
    // then fully overwritten by k_scan before k_post reads Zall.
    float* xiT = (float*)(ws + 67108864);

    (void)hipFuncSetAttribute((const void*)k_scan,
                              hipFuncAttributeMaxDynamicSharedMemorySize, SCAN_LDS);

    k_xit<<<Bc * Fc * 8, 256, 0, stream>>>(xi, xiT);
    k_pre<<<Bc, 256, 0, stream>>>(z0, A, Gw, Fz, Gz, Z0ft);
    k_spec<<<Bc * Tc, 512, 0, stream>>>(xiT, Fz, Gz, Hft);
    k_scan<<<Xc * 2, 768, SCAN_LDS, stream>>>(Wr, Wi, Hft, Z0ft, Zall);
    k_post<<<Bc * Hc * 8, 512, 0, stream>>>(Zall, out);
}